// Round 16
// baseline (5879.512 us; speedup 1.0000x reference)
//
#include <hip/hip_runtime.h>
#include <hip/hip_bf16.h>

typedef unsigned short u16;
typedef unsigned int u32;
typedef __attribute__((ext_vector_type(8))) short bf16x8;
typedef __attribute__((ext_vector_type(4))) float f32x4;

#define T_TOK 8192
#define DIN 4096
#define DOUT 4096
#define N_SEQS 4
#define N_ADPT 8
#define MAXR 64
#define CACHE_LEN 512

__device__ __forceinline__ u16 f2bf(float f) {
    u32 u = __builtin_bit_cast(u32, f);
    u += 0x7fffu + ((u >> 16) & 1u);   // RNE
    return (u16)(u >> 16);
}

__device__ __forceinline__ void load_lds16(const u16* g, u16* l) {
    __builtin_amdgcn_global_load_lds(
        (const __attribute__((address_space(1))) u32*)g,
        (__attribute__((address_space(3))) u32*)l, 16, 0, 0);
}

// ------- fused fp32->bf16 convert of x, W, a_cache + Bt gather (build_bt) -------
__global__ void cvt_all(const float* __restrict__ x, const float* __restrict__ w,
                        const float* __restrict__ a, const float* __restrict__ b_cache,
                        const int* __restrict__ rpt,
                        u16* __restrict__ xb, u16* __restrict__ wb, u16* __restrict__ ab,
                        u16* __restrict__ Bt) {
    const int n_x = T_TOK * DIN / 4, n_w = DOUT * DIN / 4, n_a = CACHE_LEN * DIN / 4;
    const int n_cvt = n_x + n_w + n_a;
    const int n_bt  = N_ADPT * 8 * DOUT;           // Bt chunks of 8 ranks
    int i = blockIdx.x * 256 + threadIdx.x;
    int stride = gridDim.x * 256;
    for (int j = i; j < n_cvt + n_bt; j += stride) {
        if (j < n_cvt) {
            const float* src; u16* dst; int k;
            if (j < n_x)            { src = x; dst = xb; k = j; }
            else if (j < n_x + n_w) { src = w; dst = wb; k = j - n_x; }
            else                    { src = a; dst = ab; k = j - n_x - n_w; }
            float4 v = reinterpret_cast<const float4*>(src)[k];
            ushort4 o;
            o.x = f2bf(v.x); o.y = f2bf(v.y); o.z = f2bf(v.z); o.w = f2bf(v.w);
            reinterpret_cast<ushort4*>(dst)[k] = o;
        } else {
            int id = j - n_cvt;                    // (a*8 + rb)*DOUT + n
            int n  = id & (DOUT - 1);
            int rb = (id >> 12) & 7;
            int ad = id >> 15;
            union { u16 u[8]; uint4 v; } pack;
            #pragma unroll
            for (int q = 0; q < 8; ++q) {
                int r = rb * 8 + q;
                int page = rpt[ad * MAXR + r];
                pack.u[q] = f2bf(b_cache[(long)page * DOUT + n]);
            }
            *reinterpret_cast<uint4*>(&Bt[((long)(ad * DOUT + n)) * MAXR + rb * 8]) = pack.v;
        }
    }
}

// ------------- xa partials: K-split x4 -> xa_part[kseg][T][64] f32 -------------
__launch_bounds__(256)
__global__ void xa_kernel(const u16* __restrict__ xb, const u16* __restrict__ ab,
                          const int* __restrict__ b_start_loc,
                          const int* __restrict__ b_adapter_ids,
                          const int* __restrict__ rpt,
                          float* __restrict__ xa_part) {
    int tblk = blockIdx.x >> 2, kseg = blockIdx.x & 3;
    int t0 = tblk * 128;
    int seg = 0;
    #pragma unroll
    for (int i = 1; i < N_SEQS; ++i) if (b_start_loc[i] <= t0) seg = i;
    int adapter = b_adapter_ids[seg];

    __shared__ __attribute__((aligned(16))) u16 As[2 * 4096];   // 2 x (128x32)
    __shared__ __attribute__((aligned(16))) u16 Bs[2 * 2048];   // 2 x (64x32)

    int tid = threadIdx.x;
    int lane = tid & 63, wave = tid >> 6;
    int lr = lane & 15, lk = lane >> 4;

    int e0 = wave * 64 + lane;               // [0,256)
    int e1 = 256 + e0;                       // [256,512)
    int ra0 = e0 >> 2, ca0 = (e0 & 3) * 8;
    int ra1 = e1 >> 2, ca1 = (e1 & 3) * 8;
    const u16* gA0 = xb + (long)(t0 + ra0) * DIN + kseg * 1024 + ca0;
    const u16* gA1 = xb + (long)(t0 + ra1) * DIN + kseg * 1024 + ca1;
    int page = rpt[adapter * MAXR + ra0];
    const u16* gB = ab + (long)page * DIN + kseg * 1024 + ca0;

    f32x4 acc[2][4] = {};

    #define XSTAGE(s, buf)                                                         \
        do {                                                                       \
            load_lds16(gA0 + (s) * 32, As + (buf) * 4096 + wave * 512);            \
            load_lds16(gA1 + (s) * 32, As + (buf) * 4096 + 2048 + wave * 512);     \
            load_lds16(gB + (s) * 32,  Bs + (buf) * 2048 + wave * 512);            \
        } while (0)

    XSTAGE(0, 0);
    for (int s = 0; s < 32; ++s) {
        int b = s & 1;
        if (s < 31) {
            XSTAGE(s + 1, b ^ 1);
            asm volatile("s_waitcnt vmcnt(3)" ::: "memory");   // step s landed; s+1 in flight
        } else {
            asm volatile("s_waitcnt vmcnt(0)" ::: "memory");
        }
        __builtin_amdgcn_s_barrier();
        __builtin_amdgcn_sched_barrier(0);

        bf16x8 af[2], bfr[4];
        #pragma unroll
        for (int m = 0; m < 2; ++m)
            af[m] = *(const bf16x8*)&As[b * 4096 + (wave * 32 + m * 16 + lr) * 32 + lk * 8];
        #pragma unroll
        for (int n = 0; n < 4; ++n)
            bfr[n] = *(const bf16x8*)&Bs[b * 2048 + (n * 16 + lr) * 32 + lk * 8];
        #pragma unroll
        for (int m = 0; m < 2; ++m)
            #pragma unroll
            for (int n = 0; n < 4; ++n)
                acc[m][n] = __builtin_amdgcn_mfma_f32_16x16x32_bf16(af[m], bfr[n], acc[m][n], 0, 0, 0);

        __builtin_amdgcn_s_barrier();          // reads done before next overwrite
        __builtin_amdgcn_sched_barrier(0);
    }
    #undef XSTAGE

    float* dst = xa_part + (long)kseg * T_TOK * MAXR;
    #pragma unroll
    for (int m = 0; m < 2; ++m) {
        int trow = t0 + wave * 32 + m * 16 + lk * 4;
        #pragma unroll
        for (int n = 0; n < 4; ++n) {
            int r = n * 16 + lr;
            #pragma unroll
            for (int j = 0; j < 4; ++j)
                dst[(long)(trow + j) * MAXR + r] = acc[m][n][j];
        }
    }
}

// ------------- xa finalize: sum 4 partials, mask, scale, cvt -> bf16 -------------
__global__ void xa_fin(const float* __restrict__ xa_part,
                       const int* __restrict__ b_start_loc,
                       const int* __restrict__ b_adapter_ids,
                       const float* __restrict__ b_scaling,
                       const int* __restrict__ ranks,
                       u16* __restrict__ xa) {
    const int N = T_TOK * MAXR;               // 524288
    int i = blockIdx.x * 256 + threadIdx.x;
    if (i >= N) return;
    int t = i >> 6, r = i & 63;
    int seg = 0;
    #pragma unroll
    for (int s = 1; s < N_SEQS; ++s) if (b_start_loc[s] <= t) seg = s;
    int adapter = b_adapter_ids[seg];
    float v = xa_part[i] + xa_part[N + i] + xa_part[2 * N + i] + xa_part[3 * N + i];
    v = (r < ranks[adapter]) ? v * b_scaling[seg] : 0.0f;
    xa[i] = f2bf(v);
}

// ------------- main GEMM: 256x256, BK=32, 3-buffer depth-2 pipeline, ONE barrier/tile -------------
// R16 change: 2 buffers/2 barriers -> 3 buffers (96 KiB)/1 barrier per K-tile.
// iter t: STAGE(t+2 -> buf[(t+2)%3]); vmcnt(4)[t+1 landed, t+2 in flight];
//         lgkmcnt(0)[my READF(t) from iter t-1 done]; s_barrier;
//         READF(t+1 <- buf[(t+1)%3]); MFMA(tile t frags).
// Overwrite safety: buf[t%3] re-staged at iter t+1, after all readers of tile t
// lgkm'd + crossed iter t's barrier. Tail ghost-free: t=126/127 stage LoRA tiles.
__launch_bounds__(512, 2)
__global__ void gemm256_kernel(const u16* __restrict__ xb, const u16* __restrict__ wb,
                               const float* __restrict__ bias,
                               const u16* __restrict__ xa, const u16* __restrict__ Bt,
                               const int* __restrict__ b_start_loc,
                               const int* __restrict__ b_adapter_ids,
                               float* __restrict__ out) {
    __shared__ __attribute__((aligned(16))) u16 lds[49152];   // 96 KiB: 3 buf x (A 16KB + B 16KB)

    // T1: XCD-aware swizzle (nwg=512 % 8 == 0 -> bijective)
    int bid = blockIdx.x;
    int wgid = (bid & 7) * 64 + (bid >> 3);
    int mt = wgid >> 4, nt = wgid & 15;
    int brow = mt * 256, bcol = nt * 256;

    int seg = 0;
    #pragma unroll
    for (int i = 1; i < N_SEQS; ++i) if (b_start_loc[i] <= brow) seg = i;
    int adapter = b_adapter_ids[seg];

    int tid = threadIdx.x;
    int lane = tid & 63, wave = tid >> 6;
    int wm = wave >> 2, wn = wave & 3;       // 2x4 wave grid, per-wave C = 128x64
    int lr = lane & 15, lk = lane >> 4;

    // ---- staging geometry (linear LDS dest, pre-swizzled source; R6/R8-verified) ----
    int lsw = (tid & 7) ^ ((tid >> 3) & 7);
    int c8  = (lsw & 3) * 8;
    int r0  = (tid >> 3) * 2 + (lsw >> 2);            // q=0 global row; q=1 adds 128
    const long odA0 = (long)(brow + r0) * DIN + c8;           // xb, q=0
    const long odA1 = odA0 + 128L * DIN;                      // xb, q=1
    const long odB0 = (long)(bcol + r0) * DIN + c8;           // wb
    const long odB1 = odB0 + 128L * DIN;
    const long o6A0 = (long)(brow + r0) * MAXR + c8;          // xa (LoRA)
    const long o6A1 = o6A0 + 128L * MAXR;
    const long o6B0 = (long)(adapter * DOUT + bcol + r0) * MAXR + c8;  // Bt
    const long o6B1 = o6B0 + 128L * MAXR;

    // buffer bi (u16 units): A at bi*16384, B at bi*16384 + 8192 (each half-tile +4096)
    #define STAGE(T, bi)                                                           \
        do {                                                                       \
            u16* dA = lds + (bi) * 16384 + tid * 8;                                \
            u16* dB = lds + (bi) * 16384 + 8192 + tid * 8;                         \
            long ko = (long)(T) * 32;                                              \
            load_lds16(xb + odA0 + ko, dA);                                        \
            load_lds16(xb + odA1 + ko, dA + 4096);                                 \
            load_lds16(wb + odB0 + ko, dB);                                        \
            load_lds16(wb + odB1 + ko, dB + 4096);                                 \
        } while (0)

    #define STAGE_LORA(RT, bi)                                                     \
        do {                                                                       \
            u16* dA = lds + (bi) * 16384 + tid * 8;                                \
            u16* dB = lds + (bi) * 16384 + 8192 + tid * 8;                         \
            long ko = (long)(RT) * 32;                                             \
            load_lds16(xa + o6A0 + ko, dA);                                        \
            load_lds16(xa + o6A1 + ko, dA + 4096);                                 \
            load_lds16(Bt + o6B0 + ko, dB);                                        \
            load_lds16(Bt + o6B1 + ko, dB + 4096);                                 \
        } while (0)

    // lane-invariant byte offset inside a [64-storage-row x 128 B] half (R6-verified)
    const int laneByte = (lr >> 1) * 128 + 16 * ((((lr & 1) << 2) + lk) ^ (lr >> 1));
    const char* ldsc = (const char*)lds;
    const int cA = wm * 8192 + laneByte;              // + bi*32768 bytes
    const int cB = 16384 + wn * 4096 + laneByte;      // + bi*32768 bytes

    #define READF(FA, FB, bi)                                                      \
        do {                                                                       \
            const char* pA = ldsc + (bi) * 32768 + cA;                             \
            const char* pB = ldsc + (bi) * 32768 + cB;                             \
            _Pragma("unroll")                                                      \
            for (int ni = 0; ni < 4; ++ni) FB[ni] = *(const bf16x8*)(pB + ni * 1024); \
            _Pragma("unroll")                                                      \
            for (int mi = 0; mi < 8; ++mi) FA[mi] = *(const bf16x8*)(pA + mi * 1024); \
        } while (0)

    #define MFMA32(FA, FB)                                                         \
        do {                                                                       \
            _Pragma("unroll")                                                      \
            for (int mi = 0; mi < 8; ++mi)                                         \
                _Pragma("unroll")                                                  \
                for (int ni = 0; ni < 4; ++ni)                                     \
                    acc[mi][ni] = __builtin_amdgcn_mfma_f32_16x16x32_bf16(         \
                        FA[mi], FB[ni], acc[mi][ni], 0, 0, 0);                     \
        } while (0)

    f32x4 acc[8][4] = {};
    bf16x8 fA0[8], fB0[4], fA1[8], fB1[4];

    // ---- prologue: stage tiles 0,1; preload tile-0 fragments ----
    STAGE(0, 0);
    STAGE(1, 1);
    asm volatile("s_waitcnt vmcnt(4)" ::: "memory");   // tile0 landed; tile1 in flight
    __builtin_amdgcn_sched_barrier(0);
    __builtin_amdgcn_s_barrier();
    READF(fA0, fB0, 0);

    // ---- hot loop: one barrier per K-tile; depth-2 DMA prefetch ----
    for (int t = 0; t < 128; ++t) {
        int T2 = t + 2;
        int bi2 = T2 % 3;
        if (T2 < 128) STAGE(T2, bi2);
        else          STAGE_LORA(T2 - 128, bi2);       // t=126 -> LoRA0, t=127 -> LoRA1
        asm volatile("s_waitcnt vmcnt(4)" ::: "memory");   // tile t+1 landed; t+2 in flight
        asm volatile("s_waitcnt lgkmcnt(0)" ::: "memory"); // my READF(t) (iter t-1) done
        __builtin_amdgcn_sched_barrier(0);
        __builtin_amdgcn_s_barrier();                  // publish t+1; license overwrite of buf[t%3] next iter
        int bi1 = (t + 1) % 3;
        if (t & 1) { READF(fA0, fB0, bi1); MFMA32(fA1, fB1); }
        else       { READF(fA1, fB1, bi1); MFMA32(fA0, fB0); }
    }

    // ---- final: tile 128 frags in set0 (read at t=127); tile 129 in buf[129%3=0] ----
    asm volatile("s_waitcnt vmcnt(0)" ::: "memory");   // LoRA tile 129 landed
    asm volatile("s_waitcnt lgkmcnt(0)" ::: "memory");
    __builtin_amdgcn_sched_barrier(0);
    __builtin_amdgcn_s_barrier();
    READF(fA1, fB1, 0);
    MFMA32(fA0, fB0);                                  // LoRA tile 128
    asm volatile("s_waitcnt lgkmcnt(0)" ::: "memory");
    __builtin_amdgcn_sched_barrier(0);
    MFMA32(fA1, fB1);                                  // LoRA tile 129

    #undef STAGE
    #undef STAGE_LORA
    #undef READF
    #undef MFMA32

    // ---- epilogue: + bias, fp32 store ----
    #pragma unroll
    for (int m = 0; m < 8; ++m) {
        int orow = brow + wm * 128 + m * 16 + lk * 4;
        #pragma unroll
        for (int n = 0; n < 4; ++n) {
            int ocol = bcol + wn * 64 + n * 16 + lr;
            float bv = bias[ocol];
            #pragma unroll
            for (int j = 0; j < 4; ++j)
                out[(long)(orow + j) * DOUT + ocol] = acc[m][n][j] + bv;
        }
    }
}

extern "C" void kernel_launch(void* const* d_in, const int* in_sizes, int n_in,
                              void* d_out, int out_size, void* d_ws, size_t ws_size,
                              hipStream_t stream) {
    const float* x          = (const float*)d_in[0];
    const float* weight     = (const float*)d_in[1];
    const float* bias       = (const float*)d_in[2];
    const float* a_cache    = (const float*)d_in[3];
    const float* b_cache    = (const float*)d_in[4];
    const int*   b_start    = (const int*)d_in[5];
    const int*   b_adapter  = (const int*)d_in[6];
    const float* b_scaling  = (const float*)d_in[7];
    const int*   rpt        = (const int*)d_in[8];
    const int*   ranks      = (const int*)d_in[9];
    float* out = (float*)d_out;

    char* ws = (char*)d_ws;
    u16*   xb      = (u16*)ws;   ws += (size_t)T_TOK * DIN * 2;          // 64 MiB
    u16*   wb      = (u16*)ws;   ws += (size_t)DOUT * DIN * 2;           // 32 MiB
    u16*   ab      = (u16*)ws;   ws += (size_t)CACHE_LEN * DIN * 2;      // 4 MiB
    u16*   Bt      = (u16*)ws;   ws += (size_t)N_ADPT * DOUT * MAXR * 2; // 4 MiB
    u16*   xa      = (u16*)ws;   ws += (size_t)T_TOK * MAXR * 2;         // 1 MiB
    float* xa_part = (float*)ws; ws += (size_t)4 * T_TOK * MAXR * 4;     // 8 MiB

    cvt_all<<<2048, 256, 0, stream>>>(x, weight, a_cache, b_cache, rpt, xb, wb, ab, Bt);
    xa_kernel<<<(T_TOK / 128) * 4, 256, 0, stream>>>(xb, ab, b_start, b_adapter, rpt, xa_part);
    xa_fin<<<(T_TOK * MAXR + 255) / 256, 256, 0, stream>>>(xa_part, b_start, b_adapter, b_scaling, ranks, xa);
    gemm256_kernel<<<(T_TOK / 256) * (DOUT / 256), 512, 0, stream>>>(xb, wb, bias, xa, Bt, b_start, b_adapter, out);
}

// Round 17
// 319.352 us; speedup vs baseline: 18.4107x; 18.4107x over previous
//
#include <hip/hip_runtime.h>
#include <hip/hip_bf16.h>

typedef unsigned short u16;
typedef unsigned int u32;
typedef __attribute__((ext_vector_type(8))) short bf16x8;
typedef __attribute__((ext_vector_type(4))) float f32x4;

#define T_TOK 8192
#define DIN 4096
#define DOUT 4096
#define N_SEQS 4
#define N_ADPT 8
#define MAXR 64
#define CACHE_LEN 512

__device__ __forceinline__ u16 f2bf(float f) {
    u32 u = __builtin_bit_cast(u32, f);
    u += 0x7fffu + ((u >> 16) & 1u);   // RNE
    return (u16)(u >> 16);
}

__device__ __forceinline__ void load_lds16(const u16* g, u16* l) {
    __builtin_amdgcn_global_load_lds(
        (const __attribute__((address_space(1))) u32*)g,
        (__attribute__((address_space(3))) u32*)l, 16, 0, 0);
}

// ------- fused fp32->bf16 convert of x, W, a_cache + Bt gather (build_bt) -------
__global__ void cvt_all(const float* __restrict__ x, const float* __restrict__ w,
                        const float* __restrict__ a, const float* __restrict__ b_cache,
                        const int* __restrict__ rpt,
                        u16* __restrict__ xb, u16* __restrict__ wb, u16* __restrict__ ab,
                        u16* __restrict__ Bt) {
    const int n_x = T_TOK * DIN / 4, n_w = DOUT * DIN / 4, n_a = CACHE_LEN * DIN / 4;
    const int n_cvt = n_x + n_w + n_a;
    const int n_bt  = N_ADPT * 8 * DOUT;           // Bt chunks of 8 ranks
    int i = blockIdx.x * 256 + threadIdx.x;
    int stride = gridDim.x * 256;
    for (int j = i; j < n_cvt + n_bt; j += stride) {
        if (j < n_cvt) {
            const float* src; u16* dst; int k;
            if (j < n_x)            { src = x; dst = xb; k = j; }
            else if (j < n_x + n_w) { src = w; dst = wb; k = j - n_x; }
            else                    { src = a; dst = ab; k = j - n_x - n_w; }
            float4 v = reinterpret_cast<const float4*>(src)[k];
            ushort4 o;
            o.x = f2bf(v.x); o.y = f2bf(v.y); o.z = f2bf(v.z); o.w = f2bf(v.w);
            reinterpret_cast<ushort4*>(dst)[k] = o;
        } else {
            int id = j - n_cvt;                    // (a*8 + rb)*DOUT + n
            int n  = id & (DOUT - 1);
            int rb = (id >> 12) & 7;
            int ad = id >> 15;
            union { u16 u[8]; uint4 v; } pack;
            #pragma unroll
            for (int q = 0; q < 8; ++q) {
                int r = rb * 8 + q;
                int page = rpt[ad * MAXR + r];
                pack.u[q] = f2bf(b_cache[(long)page * DOUT + n]);
            }
            *reinterpret_cast<uint4*>(&Bt[((long)(ad * DOUT + n)) * MAXR + rb * 8]) = pack.v;
        }
    }
}

// ------------- xa partials: K-split x4 -> xa_part[kseg][T][64] f32 -------------
__launch_bounds__(256)
__global__ void xa_kernel(const u16* __restrict__ xb, const u16* __restrict__ ab,
                          const int* __restrict__ b_start_loc,
                          const int* __restrict__ b_adapter_ids,
                          const int* __restrict__ rpt,
                          float* __restrict__ xa_part) {
    int tblk = blockIdx.x >> 2, kseg = blockIdx.x & 3;
    int t0 = tblk * 128;
    int seg = 0;
    #pragma unroll
    for (int i = 1; i < N_SEQS; ++i) if (b_start_loc[i] <= t0) seg = i;
    int adapter = b_adapter_ids[seg];

    __shared__ __attribute__((aligned(16))) u16 As[2 * 4096];   // 2 x (128x32)
    __shared__ __attribute__((aligned(16))) u16 Bs[2 * 2048];   // 2 x (64x32)

    int tid = threadIdx.x;
    int lane = tid & 63, wave = tid >> 6;
    int lr = lane & 15, lk = lane >> 4;

    int e0 = wave * 64 + lane;               // [0,256)
    int e1 = 256 + e0;                       // [256,512)
    int ra0 = e0 >> 2, ca0 = (e0 & 3) * 8;
    int ra1 = e1 >> 2, ca1 = (e1 & 3) * 8;
    const u16* gA0 = xb + (long)(t0 + ra0) * DIN + kseg * 1024 + ca0;
    const u16* gA1 = xb + (long)(t0 + ra1) * DIN + kseg * 1024 + ca1;
    int page = rpt[adapter * MAXR + ra0];
    const u16* gB = ab + (long)page * DIN + kseg * 1024 + ca0;

    f32x4 acc[2][4] = {};

    #define XSTAGE(s, buf)                                                         \
        do {                                                                       \
            load_lds16(gA0 + (s) * 32, As + (buf) * 4096 + wave * 512);            \
            load_lds16(gA1 + (s) * 32, As + (buf) * 4096 + 2048 + wave * 512);     \
            load_lds16(gB + (s) * 32,  Bs + (buf) * 2048 + wave * 512);            \
        } while (0)

    XSTAGE(0, 0);
    for (int s = 0; s < 32; ++s) {
        int b = s & 1;
        if (s < 31) {
            XSTAGE(s + 1, b ^ 1);
            asm volatile("s_waitcnt vmcnt(3)" ::: "memory");   // step s landed; s+1 in flight
        } else {
            asm volatile("s_waitcnt vmcnt(0)" ::: "memory");
        }
        __builtin_amdgcn_s_barrier();
        __builtin_amdgcn_sched_barrier(0);

        bf16x8 af[2], bfr[4];
        #pragma unroll
        for (int m = 0; m < 2; ++m)
            af[m] = *(const bf16x8*)&As[b * 4096 + (wave * 32 + m * 16 + lr) * 32 + lk * 8];
        #pragma unroll
        for (int n = 0; n < 4; ++n)
            bfr[n] = *(const bf16x8*)&Bs[b * 2048 + (n * 16 + lr) * 32 + lk * 8];
        #pragma unroll
        for (int m = 0; m < 2; ++m)
            #pragma unroll
            for (int n = 0; n < 4; ++n)
                acc[m][n] = __builtin_amdgcn_mfma_f32_16x16x32_bf16(af[m], bfr[n], acc[m][n], 0, 0, 0);

        __builtin_amdgcn_s_barrier();          // reads done before next overwrite
        __builtin_amdgcn_sched_barrier(0);
    }
    #undef XSTAGE

    float* dst = xa_part + (long)kseg * T_TOK * MAXR;
    #pragma unroll
    for (int m = 0; m < 2; ++m) {
        int trow = t0 + wave * 32 + m * 16 + lk * 4;
        #pragma unroll
        for (int n = 0; n < 4; ++n) {
            int r = n * 16 + lr;
            #pragma unroll
            for (int j = 0; j < 4; ++j)
                dst[(long)(trow + j) * MAXR + r] = acc[m][n][j];
        }
    }
}

// ------------- xa finalize: sum 4 partials, mask, scale, cvt -> bf16 -------------
__global__ void xa_fin(const float* __restrict__ xa_part,
                       const int* __restrict__ b_start_loc,
                       const int* __restrict__ b_adapter_ids,
                       const float* __restrict__ b_scaling,
                       const int* __restrict__ ranks,
                       u16* __restrict__ xa) {
    const int N = T_TOK * MAXR;               // 524288
    int i = blockIdx.x * 256 + threadIdx.x;
    if (i >= N) return;
    int t = i >> 6, r = i & 63;
    int seg = 0;
    #pragma unroll
    for (int s = 1; s < N_SEQS; ++s) if (b_start_loc[s] <= t) seg = s;
    int adapter = b_adapter_ids[seg];
    float v = xa_part[i] + xa_part[N + i] + xa_part[2 * N + i] + xa_part[3 * N + i];
    v = (r < ranks[adapter]) ? v * b_scaling[seg] : 0.0f;
    xa[i] = f2bf(v);
}

// ------------- main GEMM: 256x256, BK=32, register-pipelined (R15 exact revert) -------------
// R17: bit-for-bit revert to R15 (320.4 us verified; gemm ~248 us, MfmaUtil 51%).
// R16's 3-buffer/1-barrier variant spilled frag sets to scratch (28 GB traffic) via
// a runtime branch-selected READF (rule #20), and is arithmetically a loss anyway
// (>=96 KiB LDS kills the 2-block/CU overlap that puts R15 below strict pipe-sum).
__launch_bounds__(512, 2)
__global__ void gemm256_kernel(const u16* __restrict__ xb, const u16* __restrict__ wb,
                               const float* __restrict__ bias,
                               const u16* __restrict__ xa, const u16* __restrict__ Bt,
                               const int* __restrict__ b_start_loc,
                               const int* __restrict__ b_adapter_ids,
                               float* __restrict__ out) {
    __shared__ __attribute__((aligned(16))) u16 lds[32768];   // 64 KiB: 2 buf x (A 8K + B 8K u16)

    // T1: XCD-aware swizzle (nwg=512 % 8 == 0 -> bijective)
    int bid = blockIdx.x;
    int wgid = (bid & 7) * 64 + (bid >> 3);
    int mt = wgid >> 4, nt = wgid & 15;
    int brow = mt * 256, bcol = nt * 256;

    int seg = 0;
    #pragma unroll
    for (int i = 1; i < N_SEQS; ++i) if (b_start_loc[i] <= brow) seg = i;
    int adapter = b_adapter_ids[seg];

    int tid = threadIdx.x;
    int lane = tid & 63, wave = tid >> 6;
    int wm = wave >> 2, wn = wave & 3;       // 2x4 wave grid, per-wave C = 128x64
    int lr = lane & 15, lk = lane >> 4;

    // ---- staging geometry (linear LDS dest, pre-swizzled source; R6/R8-verified) ----
    int lsw = (tid & 7) ^ ((tid >> 3) & 7);
    int c8  = (lsw & 3) * 8;
    int r0  = (tid >> 3) * 2 + (lsw >> 2);            // q=0 global row; q=1 adds 128
    const long odA0 = (long)(brow + r0) * DIN + c8;           // xb, q=0
    const long odA1 = odA0 + 128L * DIN;                      // xb, q=1
    const long odB0 = (long)(bcol + r0) * DIN + c8;           // wb
    const long odB1 = odB0 + 128L * DIN;
    const long o6A0 = (long)(brow + r0) * MAXR + c8;          // xa (LoRA)
    const long o6A1 = o6A0 + 128L * MAXR;
    const long o6B0 = (long)(adapter * DOUT + bcol + r0) * MAXR + c8;  // Bt
    const long o6B1 = o6B0 + 128L * MAXR;

    #define STAGE(T, buf)                                                          \
        do {                                                                       \
            u16* dA = lds + (buf) * 8192 + tid * 8;                                \
            u16* dB = lds + 16384 + (buf) * 8192 + tid * 8;                        \
            long ko = (long)(T) * 32;                                              \
            load_lds16(xb + odA0 + ko, dA);                                        \
            load_lds16(xb + odA1 + ko, dA + 4096);                                 \
            load_lds16(wb + odB0 + ko, dB);                                        \
            load_lds16(wb + odB1 + ko, dB + 4096);                                 \
        } while (0)

    #define STAGE_LORA(RT, buf)                                                    \
        do {                                                                       \
            u16* dA = lds + (buf) * 8192 + tid * 8;                                \
            u16* dB = lds + 16384 + (buf) * 8192 + tid * 8;                        \
            long ko = (long)(RT) * 32;                                             \
            load_lds16(xa + o6A0 + ko, dA);                                        \
            load_lds16(xa + o6A1 + ko, dA + 4096);                                 \
            load_lds16(Bt + o6B0 + ko, dB);                                        \
            load_lds16(Bt + o6B1 + ko, dB + 4096);                                 \
        } while (0)

    // lane-invariant byte offset inside a [64-storage-row x 128 B] tile (R6-verified)
    const int laneByte = (lr >> 1) * 128 + 16 * ((((lr & 1) << 2) + lk) ^ (lr >> 1));
    const char* ldsc = (const char*)lds;
    const int cA = wm * 8192 + laneByte;              // + buf*16384 bytes
    const int cB = 32768 + wn * 4096 + laneByte;      // + buf*16384 bytes

    #define READF(FA, FB, par)                                                     \
        do {                                                                       \
            const char* pA = ldsc + (par) * 16384 + cA;                            \
            const char* pB = ldsc + (par) * 16384 + cB;                            \
            _Pragma("unroll")                                                      \
            for (int ni = 0; ni < 4; ++ni) FB[ni] = *(const bf16x8*)(pB + ni * 1024); \
            _Pragma("unroll")                                                      \
            for (int mi = 0; mi < 8; ++mi) FA[mi] = *(const bf16x8*)(pA + mi * 1024); \
        } while (0)

    #define MFMA32(FA, FB)                                                         \
        do {                                                                       \
            _Pragma("unroll")                                                      \
            for (int mi = 0; mi < 8; ++mi)                                         \
                _Pragma("unroll")                                                  \
                for (int ni = 0; ni < 4; ++ni)                                     \
                    acc[mi][ni] = __builtin_amdgcn_mfma_f32_16x16x32_bf16(         \
                        FA[mi], FB[ni], acc[mi][ni], 0, 0, 0);                     \
        } while (0)

    #define ENDBAR()                                                               \
        do {                                                                       \
            asm volatile("s_waitcnt lgkmcnt(0)" ::: "memory");                     \
            __builtin_amdgcn_sched_barrier(0);                                     \
            __builtin_amdgcn_s_barrier();                                          \
        } while (0)

    f32x4 acc[8][4] = {};
    bf16x8 fA0[8], fB0[4], fA1[8], fB1[4];

    // ---- prologue: stage tiles 0,1; preload tile-0 fragments ----
    STAGE(0, 0);
    STAGE(1, 1);
    asm volatile("s_waitcnt vmcnt(4)" ::: "memory");   // tile0 landed; tile1 in flight
    __builtin_amdgcn_s_barrier();
    READF(fA0, fB0, 0);
    ENDBAR();

    // ---- hot loop: 128 weight K-tiles, branch-free STAGE, constant trip count ----
    for (int t = 0; t < 128; t += 2) {
        // even half: consume set0 (tile t), preload set1 (tile t+1)
        if (t + 2 < 128) STAGE(t + 2, 0); else STAGE_LORA(0, 0);   // tile t+2 -> buf0
        asm volatile("s_waitcnt vmcnt(4)" ::: "memory");           // tile t+1 landed
        __builtin_amdgcn_s_barrier();
        READF(fA1, fB1, 1);
        MFMA32(fA0, fB0);
        ENDBAR();

        // odd half: consume set1 (tile t+1), preload set0 (tile t+2)
        if (t + 3 < 128) STAGE(t + 3, 1); else STAGE_LORA(1, 1);   // tile t+3 -> buf1
        asm volatile("s_waitcnt vmcnt(4)" ::: "memory");
        __builtin_amdgcn_s_barrier();
        READF(fA0, fB0, 0);
        MFMA32(fA1, fB1);
        ENDBAR();
    }

    // ---- LoRA epilogue: K-tiles 128 (in buf0, frags in set0) and 129 (buf1) ----
    asm volatile("s_waitcnt vmcnt(0)" ::: "memory");   // LoRA tile 129 landed
    __builtin_amdgcn_s_barrier();
    READF(fA1, fB1, 1);
    MFMA32(fA0, fB0);                                  // LoRA tile 128
    asm volatile("s_waitcnt lgkmcnt(0)" ::: "memory");
    MFMA32(fA1, fB1);                                  // LoRA tile 129

    #undef STAGE
    #undef STAGE_LORA
    #undef READF
    #undef MFMA32
    #undef ENDBAR

    // ---- epilogue: + bias, fp32 store ----
    #pragma unroll
    for (int m = 0; m < 8; ++m) {
        int orow = brow + wm * 128 + m * 16 + lk * 4;
        #pragma unroll
        for (int n = 0; n < 4; ++n) {
            int ocol = bcol + wn * 64 + n * 16 + lr;
            float bv = bias[ocol];
            #pragma unroll
            for (int j = 0; j < 4; ++j)
                out[(long)(orow + j) * DOUT + ocol] = acc[m][n][j] + bv;
        }
    }
}

extern "C" void kernel_launch(void* const* d_in, const int* in_sizes, int n_in,
                              void* d_out, int out_size, void* d_ws, size_t ws_size,
                              hipStream_t stream) {
    const float* x          = (const float*)d_in[0];
    const float* weight     = (const float*)d_in[1];
    const float* bias       = (const float*)d_in[2];
    const float* a_cache    = (const float*)d_in[3];
    const float* b_cache    = (const float*)d_in[4];
    const int*   b_start    = (const int*)d_in[5];
    const int*   b_adapter  = (const int*)d_in[6];
    const float* b_scaling  = (const float*)d_in[7];
    const int*   rpt        = (const int*)d_in[8];
    const int*   ranks      = (const int*)d_in[9];
    float* out = (float*)d_out;

    char* ws = (char*)d_ws;
    u16*   xb      = (u16*)ws;   ws += (size_t)T_TOK * DIN * 2;          // 64 MiB
    u16*   wb      = (u16*)ws;   ws += (size_t)DOUT * DIN * 2;           // 32 MiB
    u16*   ab      = (u16*)ws;   ws += (size_t)CACHE_LEN * DIN * 2;      // 4 MiB
    u16*   Bt      = (u16*)ws;   ws += (size_t)N_ADPT * DOUT * MAXR * 2; // 4 MiB
    u16*   xa      = (u16*)ws;   ws += (size_t)T_TOK * MAXR * 2;         // 1 MiB
    float* xa_part = (float*)ws; ws += (size_t)4 * T_TOK * MAXR * 4;     // 8 MiB

    cvt_all<<<2048, 256, 0, stream>>>(x, weight, a_cache, b_cache, rpt, xb, wb, ab, Bt);
    xa_kernel<<<(T_TOK / 128) * 4, 256, 0, stream>>>(xb, ab, b_start, b_adapter, rpt, xa_part);
    xa_fin<<<(T_TOK * MAXR + 255) / 256, 256, 0, stream>>>(xa_part, b_start, b_adapter, b_scaling, ranks, xa);
    gemm256_kernel<<<(T_TOK / 256) * (DOUT / 256), 512, 0, stream>>>(xb, wb, bias, xa, Bt, b_start, b_adapter, out);
}